// Round 5
// baseline (64474.042 us; speedup 1.0000x reference)
//
#include <hip/hip_runtime.h>
#include <math.h>
#include <stdint.h>

#define T_STEPS 2048
#define XDIM 118
#define EMBD 128
#define HD 1536
#define NA 96
#define NB 128
#define NBLK (NA + NB)

// counter words, each in its own 64B line: ACTR[16] at word l*16, BCTR[16] at 256+l*16
#define EP_ACTR 0
#define EP_BCTR 256
#define EP_N    512

// dynamic LDS: B needs 3072(xv) + 36864(weights) + 72 = 40008 words = 160032 B
#define SMEM_BYTES 160032

struct Params {
  const float *x, *h0in, *c0in;
  const float *Wih0, *Whh0, *bih0, *bhh0;
  const float *Wih1, *Whh1, *bih1, *bhh1;
  const float *Whl, *bhl, *Wout, *bout, *Wmap, *bmap;
  float *PRE, *Wc, *bc, *h0buf, *h1buf, *PART;
  uint32_t *ep;
  float *out;
};

__device__ __forceinline__ float bf_lo(uint32_t u){ return __uint_as_float(u << 16); }
__device__ __forceinline__ float bf_hi(uint32_t u){ return __uint_as_float(u & 0xffff0000u); }
__device__ __forceinline__ uint32_t packbf(float a, float b){
  uint32_t ua = __float_as_uint(a), ub = __float_as_uint(b);
  ua = (ua + 0x7fffu + ((ua >> 16) & 1u)) >> 16;           // RNE bf16 (low half)
  ub = (ub + 0x7fffu + ((ub >> 16) & 1u)) & 0xffff0000u;   // RNE bf16 (high half)
  return (ua & 0xffffu) | ub;
}
// Cross-block data via agent-scope relaxed atomics (served at the device coherence
// point -> never stale). data->flag order: __syncthreads() drains vmcnt (stores
// acked) before the counter atomicAdd. Counters are monotone; 16 words/direction
// spread over 16 lines -> low RMW contention, one 16-lane load polls all.
__device__ __forceinline__ float gload(const float* p){
  return __hip_atomic_load(p, __ATOMIC_RELAXED, __HIP_MEMORY_SCOPE_AGENT);
}
__device__ __forceinline__ void gstore(float* p, float v){
  __hip_atomic_store(p, v, __ATOMIC_RELAXED, __HIP_MEMORY_SCOPE_AGENT);
}
__device__ __forceinline__ uint32_t gloadu(const uint32_t* p){
  return __hip_atomic_load(p, __ATOMIC_RELAXED, __HIP_MEMORY_SCOPE_AGENT);
}
__device__ __forceinline__ void ctradd(uint32_t* p){
  (void)__hip_atomic_fetch_add(p, 1u, __ATOMIC_RELAXED, __HIP_MEMORY_SCOPE_AGENT);
}
__device__ __forceinline__ float sigm(float x){ return 1.f / (1.f + __expf(-x)); }

// ---------------- group A: layer 0 + replicated head (96 blocks, 16 outputs) ----------------
// wave w owns 4 gates of output O=bid*16+w. K=1664 in 13 slots of 128 (k=128p+2l,+1).
// Regs p=0..5; LDS q=0..2 (p=6..11); wremb=p12 (emb). Head (PART-reduce, softmax,
// Wmap@p) computed locally every step -> emb never leaves the block.
__device__ __forceinline__ float asrc(const Params& P, int r, int k){
  if (k < HD) return P.Whh0[(size_t)r * HD + k];
  return P.Wih0[(size_t)r * (XDIM + EMBD) + XDIM + (k - HD)];
}
__device__ void run_A(const Params& P, int bid, uint32_t* smem){
  const int tid = threadIdx.x;
  const int w = tid >> 6, l = tid & 63;
  const int O = bid * 16 + w;
  float* xv = (float*)smem;                   // [0,1664): h0 ++ emb
  uint2* wl2 = (uint2*)(smem + 1664);         // 3q*4g*1024 uint2 -> [1664, 26240)
  uint32_t* wmT = smem + 26240;               // bf16-packed Wmap^T, 8192 -> [26240,34432)
  float* pr2 = (float*)(smem + 34432);        // 2048 scratch (PART-red / emb partials)
  float* lg   = (float*)(smem + 36480);       // 128
  float* plds = (float*)(smem + 36608);       // 128
  float* bcs  = (float*)(smem + 36736);       // 128
  float* bmaps= (float*)(smem + 36864);       // 128
  float* red2 = (float*)(smem + 36992);       // 2
  uint32_t wr[4][6], wremb[4];
#pragma unroll
  for (int g = 0; g < 4; ++g){
    int r = g * HD + O;
#pragma unroll
    for (int p = 0; p < 6; ++p)
      wr[g][p] = packbf(asrc(P, r, 128 * p + 2 * l), asrc(P, r, 128 * p + 2 * l + 1));
#pragma unroll
    for (int q = 0; q < 3; ++q){
      uint2 u;
      u.x = packbf(asrc(P, r, 128 * (6 + 2 * q) + 2 * l), asrc(P, r, 128 * (6 + 2 * q) + 2 * l + 1));
      u.y = packbf(asrc(P, r, 128 * (7 + 2 * q) + 2 * l), asrc(P, r, 128 * (7 + 2 * q) + 2 * l + 1));
      wl2[(q * 4 + g) * 1024 + tid] = u;
    }
    wremb[g] = packbf(asrc(P, r, 1536 + 2 * l), asrc(P, r, 1537 + 2 * l));
  }
  for (int idx = tid; idx < 8192; idx += 1024){   // wmT[k*64+e2] = pack(Wmap[2e2][k], Wmap[2e2+1][k])
    int e2 = idx & 63, k = idx >> 6;
    wmT[idx] = packbf(P.Wmap[(size_t)(2 * e2) * 128 + k], P.Wmap[(size_t)(2 * e2 + 1) * 128 + k]);
  }
  if (tid < 128){ bcs[tid] = P.bc[tid]; bmaps[tid] = P.bmap[tid]; }
  float cst = P.c0in[O];
  int alive = 1;                                   // wave-0 lanes only
  __syncthreads();
  for (int t = 0; t < T_STEPS; ++t){
    const float* pre = P.PRE + (size_t)t * 6144;   // prefetch early
    float q0 = pre[O], q1 = pre[HD + O], q2 = pre[2 * HD + O], q3 = pre[3 * HD + O];
    if (w == 0 && alive){                          // pre-wait: all-A(t-1) -> ACTR >= 6t
      uint32_t tgt = 6u * (uint32_t)t, n = 0;
      while (1){
        uint32_t v = (l < 16) ? gloadu(P.ep + EP_ACTR + l * 16) : tgt;
        if (__all(v >= tgt)) break;
        if (++n > 5000000u){ alive = 0; break; }
      }
    }
    __syncthreads();
    const float* hp = P.h0buf + (((t & 1) ^ 1) * HD);
    xv[tid] = gload(hp + tid);
    if (tid < 512) xv[1024 + tid] = gload(hp + 1024 + tid);
    __syncthreads();
    float a0 = 0.f, a1 = 0.f, a2 = 0.f, a3 = 0.f;
#pragma unroll
    for (int p = 0; p < 6; ++p){
      float2 x2 = *(const float2*)&xv[128 * p + 2 * l];
      uint32_t u0 = wr[0][p], u1 = wr[1][p], u2 = wr[2][p], u3 = wr[3][p];
      a0 += bf_lo(u0) * x2.x + bf_hi(u0) * x2.y;
      a1 += bf_lo(u1) * x2.x + bf_hi(u1) * x2.y;
      a2 += bf_lo(u2) * x2.x + bf_hi(u2) * x2.y;
      a3 += bf_lo(u3) * x2.x + bf_hi(u3) * x2.y;
    }
#pragma unroll
    for (int q = 0; q < 3; ++q){
      float2 xa = *(const float2*)&xv[128 * (6 + 2 * q) + 2 * l];
      float2 xb = *(const float2*)&xv[128 * (7 + 2 * q) + 2 * l];
      uint2 u0 = wl2[(q * 4 + 0) * 1024 + tid];
      uint2 u1 = wl2[(q * 4 + 1) * 1024 + tid];
      uint2 u2 = wl2[(q * 4 + 2) * 1024 + tid];
      uint2 u3 = wl2[(q * 4 + 3) * 1024 + tid];
      a0 += bf_lo(u0.x) * xa.x + bf_hi(u0.x) * xa.y + bf_lo(u0.y) * xb.x + bf_hi(u0.y) * xb.y;
      a1 += bf_lo(u1.x) * xa.x + bf_hi(u1.x) * xa.y + bf_lo(u1.y) * xb.x + bf_hi(u1.y) * xb.y;
      a2 += bf_lo(u2.x) * xa.x + bf_hi(u2.x) * xa.y + bf_lo(u2.y) * xb.x + bf_hi(u2.y) * xb.y;
      a3 += bf_lo(u3.x) * xa.x + bf_hi(u3.x) * xa.y + bf_lo(u3.y) * xb.x + bf_hi(u3.y) * xb.y;
    }
    if (w == 0 && alive){                          // main wait: all-B(t-1) -> BCTR >= 8t
      uint32_t tgt = 8u * (uint32_t)t, n = 0;
      while (1){
        uint32_t v = (l < 16) ? gloadu(P.ep + EP_BCTR + l * 16) : tgt;
        if (__all(v >= tgt)) break;
        if (++n > 5000000u){ alive = 0; break; }
      }
    }
    __syncthreads();
    if (t > 0){
      // ---- replicated head: logits(t-1) -> softmax -> out (bid 0) -> emb (local) ----
      const int j = tid & 127, b8 = tid >> 7;
      float s = 0.f;
#pragma unroll
      for (int i = 0; i < 16; ++i) s += gload(P.PART + (b8 * 16 + i) * 128 + j);
      pr2[b8 * 128 + j] = s;
      __syncthreads();
      if (tid < 128){
        float lt = bcs[tid];
#pragma unroll
        for (int i = 0; i < 8; ++i) lt += pr2[i * 128 + tid];
        lg[tid] = lt;
      }
      __syncthreads();
      if (tid < 64){
        float m = fmaxf(lg[tid], lg[tid + 64]);
#pragma unroll
        for (int k = 1; k < 64; k <<= 1) m = fmaxf(m, __shfl_xor(m, k, 64));
        float sd = __expf(lg[tid] - m) + __expf(lg[tid + 64] - m);
#pragma unroll
        for (int k = 1; k < 64; k <<= 1) sd += __shfl_xor(sd, k, 64);
        if (tid == 0){ red2[0] = m; red2[1] = 1.f / sd; }
      }
      __syncthreads();
      if (tid < 128){
        float pv = __expf(lg[tid] - red2[0]) * red2[1];
        plds[tid] = pv;
        if (bid == 0) P.out[(size_t)(t - 1) * 128 + tid] = pv;
      }
      __syncthreads();
      {   // emb[e] = bmap[e] + sum_i Wmap[e][i]*p[i]; thread (m=tid>>6, e2=tid&63)
        int e2 = tid & 63, m = tid >> 6;
        float s0 = 0.f, s1 = 0.f;
#pragma unroll
        for (int i = 0; i < 8; ++i){
          uint32_t u = wmT[(m * 8 + i) * 64 + e2];
          float p = plds[m * 8 + i];
          s0 += bf_lo(u) * p;
          s1 += bf_hi(u) * p;
        }
        *(float2*)&pr2[m * 128 + 2 * e2] = make_float2(s0, s1);
      }
      __syncthreads();
      if (tid < 128){
        float v = bmaps[tid];
#pragma unroll
        for (int m = 0; m < 16; ++m) v += pr2[m * 128 + tid];
        xv[1536 + tid] = v;
      }
    } else {
      if (tid < 128) xv[1536 + tid] = 0.f;         // emb(-1) = 0
    }
    __syncthreads();
    {   // p=12: emb slot
      float2 x2 = *(const float2*)&xv[1536 + 2 * l];
      a0 += bf_lo(wremb[0]) * x2.x + bf_hi(wremb[0]) * x2.y;
      a1 += bf_lo(wremb[1]) * x2.x + bf_hi(wremb[1]) * x2.y;
      a2 += bf_lo(wremb[2]) * x2.x + bf_hi(wremb[2]) * x2.y;
      a3 += bf_lo(wremb[3]) * x2.x + bf_hi(wremb[3]) * x2.y;
    }
#pragma unroll
    for (int m = 1; m < 64; m <<= 1){
      a0 += __shfl_xor(a0, m, 64);
      a1 += __shfl_xor(a1, m, 64);
      a2 += __shfl_xor(a2, m, 64);
      a3 += __shfl_xor(a3, m, 64);
    }
    float gi = sigm(a0 + q0);
    float gf = sigm(a1 + q1);
    float gg = tanhf(a2 + q2);
    float go = sigm(a3 + q3);
    cst = gf * cst + gi * gg;
    float hn = go * tanhf(cst);
    if (l == 0) gstore(P.h0buf + (t & 1) * HD + O, hn);
    __syncthreads();                               // drains vmcnt: h0 stores acked
    if (tid == 0) ctradd(P.ep + EP_ACTR + (bid & 15) * 16);
  }
  if (bid == 0){                                   // epilogue: out[2047] from PART(2047)
    if (w == 0 && alive){
      uint32_t tgt = 8u * (uint32_t)T_STEPS, n = 0;
      while (1){
        uint32_t v = (l < 16) ? gloadu(P.ep + EP_BCTR + l * 16) : tgt;
        if (__all(v >= tgt)) break;
        if (++n > 5000000u){ alive = 0; break; }
      }
    }
    __syncthreads();
    const int j = tid & 127, b8 = tid >> 7;
    float s = 0.f;
#pragma unroll
    for (int i = 0; i < 16; ++i) s += gload(P.PART + (b8 * 16 + i) * 128 + j);
    pr2[b8 * 128 + j] = s;
    __syncthreads();
    if (tid < 128){
      float lt = bcs[tid];
#pragma unroll
      for (int i = 0; i < 8; ++i) lt += pr2[i * 128 + tid];
      lg[tid] = lt;
    }
    __syncthreads();
    if (tid < 64){
      float m = fmaxf(lg[tid], lg[tid + 64]);
#pragma unroll
      for (int k = 1; k < 64; k <<= 1) m = fmaxf(m, __shfl_xor(m, k, 64));
      float sd = __expf(lg[tid] - m) + __expf(lg[tid + 64] - m);
#pragma unroll
      for (int k = 1; k < 64; k <<= 1) sd += __shfl_xor(sd, k, 64);
      if (tid == 0){ red2[0] = m; red2[1] = 1.f / sd; }
    }
    __syncthreads();
    if (tid < 128) P.out[(size_t)(T_STEPS - 1) * 128 + tid] = __expf(lg[tid] - red2[0]) * red2[1];
  }
}

// ---------------- group B: LSTM layer 1 (128 blocks, 12 outputs each) ----------------
// Unchanged compute from round 4; new waits: phase-1 <- BCTR>=8t (all-B(t-1)),
// phase-2 <- ACTR>=6(t+1) (all-A(t), also guarantees PART(t-1) fully consumed).
__device__ __forceinline__ float bsrc(const Params& P, int r, int k){
  if (k < HD) return P.Wih1[(size_t)r * HD + k];
  return P.Whh1[(size_t)r * HD + (k - HD)];
}
__device__ void run_B(const Params& P, int bidb, uint32_t* smem){
  const int tid = threadIdx.x;
  const int w = tid >> 6, l = tid & 63;
  const int base = bidb * 12;
  float* xv = (float*)smem;                  // 3072
  uint2* wl2 = (uint2*)(smem + 3072);        // 6q*3rows*1024 uint2 -> [3072, 39936)
  float* g1lds = (float*)(smem + 39936);     // 48
  float* c1lds = g1lds + 48;                 // 12
  float* h1lds = c1lds + 12;                 // 12
  uint32_t wr[3][12];
  float bias[3];
#pragma unroll
  for (int jj = 0; jj < 3; ++jj){
    int idx = 3 * w + jj;
    int g = idx / 12, o = idx % 12;
    int r = g * HD + base + o;
    bias[jj] = P.bih1[r] + P.bhh1[r];
#pragma unroll
    for (int p = 0; p < 12; ++p)
      wr[jj][p] = packbf(bsrc(P, r, 128 * p + 2 * l), bsrc(P, r, 128 * p + 2 * l + 1));
#pragma unroll
    for (int q = 0; q < 6; ++q){
      uint2 u;
      u.x = packbf(bsrc(P, r, 128 * (12 + 2 * q) + 2 * l), bsrc(P, r, 128 * (12 + 2 * q) + 2 * l + 1));
      u.y = packbf(bsrc(P, r, 128 * (13 + 2 * q) + 2 * l), bsrc(P, r, 128 * (13 + 2 * q) + 2 * l + 1));
      wl2[(q * 3 + jj) * 1024 + tid] = u;
    }
  }
  const int jrow = tid >> 2, cpart = tid & 3;
  float wc0 = 0.f, wc1 = 0.f, wc2 = 0.f;
  if (tid < 512){
    const float* wcp = P.Wc + (size_t)jrow * HD + base + cpart * 3;
    wc0 = wcp[0]; wc1 = wcp[1]; wc2 = wcp[2];
  }
  if (tid < 12) c1lds[tid] = P.c0in[HD + base + tid];
  int alive = 1;
  __syncthreads();
  for (int t = 0; t < T_STEPS; ++t){
    if (w == 0 && alive){                    // all-B(t-1): h1(t-1) complete, self-barrier
      uint32_t tgt = 8u * (uint32_t)t, n = 0;
      while (1){
        uint32_t v = (l < 16) ? gloadu(P.ep + EP_BCTR + l * 16) : tgt;
        if (__all(v >= tgt)) break;
        if (++n > 5000000u){ alive = 0; break; }
      }
    }
    __syncthreads();
    const float* h1p = P.h1buf + (((t & 1) ^ 1) * HD);
    xv[1536 + tid] = gload(h1p + tid);
    if (tid < 512) xv[2560 + tid] = gload(h1p + 1024 + tid);
    __syncthreads();
    float a0 = 0.f, a1 = 0.f, a2 = 0.f;
#pragma unroll
    for (int q = 0; q < 6; ++q){             // h1 side (LDS weights) — overlapped phase
      float2 xa = *(const float2*)&xv[128 * (12 + 2 * q) + 2 * l];
      float2 xb = *(const float2*)&xv[128 * (13 + 2 * q) + 2 * l];
      uint2 u0 = wl2[(q * 3 + 0) * 1024 + tid];
      uint2 u1 = wl2[(q * 3 + 1) * 1024 + tid];
      uint2 u2 = wl2[(q * 3 + 2) * 1024 + tid];
      a0 += bf_lo(u0.x) * xa.x + bf_hi(u0.x) * xa.y + bf_lo(u0.y) * xb.x + bf_hi(u0.y) * xb.y;
      a1 += bf_lo(u1.x) * xa.x + bf_hi(u1.x) * xa.y + bf_lo(u1.y) * xb.x + bf_hi(u1.y) * xb.y;
      a2 += bf_lo(u2.x) * xa.x + bf_hi(u2.x) * xa.y + bf_lo(u2.y) * xb.x + bf_hi(u2.y) * xb.y;
    }
    if (w == 0 && alive){                    // all-A(t): h0(t) ready, PART(t-1) consumed
      uint32_t tgt = 6u * (uint32_t)(t + 1), n = 0;
      while (1){
        uint32_t v = (l < 16) ? gloadu(P.ep + EP_ACTR + l * 16) : tgt;
        if (__all(v >= tgt)) break;
        if (++n > 5000000u){ alive = 0; break; }
      }
    }
    __syncthreads();
    const float* h0p = P.h0buf + (t & 1) * HD;
    xv[tid] = gload(h0p + tid);
    if (tid < 512) xv[1024 + tid] = gload(h0p + 1024 + tid);
    __syncthreads();
#pragma unroll
    for (int p = 0; p < 12; ++p){            // h0 side (reg weights) — serial phase
      float2 x2 = *(const float2*)&xv[128 * p + 2 * l];
      uint32_t u0 = wr[0][p], u1 = wr[1][p], u2 = wr[2][p];
      a0 += bf_lo(u0) * x2.x + bf_hi(u0) * x2.y;
      a1 += bf_lo(u1) * x2.x + bf_hi(u1) * x2.y;
      a2 += bf_lo(u2) * x2.x + bf_hi(u2) * x2.y;
    }
#pragma unroll
    for (int m = 1; m < 64; m <<= 1){
      a0 += __shfl_xor(a0, m, 64);
      a1 += __shfl_xor(a1, m, 64);
      a2 += __shfl_xor(a2, m, 64);
    }
    if (l == 0){
      g1lds[3 * w + 0] = a0 + bias[0];
      g1lds[3 * w + 1] = a1 + bias[1];
      g1lds[3 * w + 2] = a2 + bias[2];
    }
    __syncthreads();
    if (tid < 12){
      int o = tid;
      float gi = sigm(g1lds[o]);
      float gf = sigm(g1lds[12 + o]);
      float gg = tanhf(g1lds[24 + o]);
      float go = sigm(g1lds[36 + o]);
      float c = gf * c1lds[o] + gi * gg;
      c1lds[o] = c;
      float hn = go * tanhf(c);
      h1lds[o] = hn;
      gstore(P.h1buf + (t & 1) * HD + base + o, hn);
    }
    __syncthreads();
    if (tid < 512){
      float pp = wc0 * h1lds[cpart * 3] + wc1 * h1lds[cpart * 3 + 1] + wc2 * h1lds[cpart * 3 + 2];
      pp += __shfl_xor(pp, 1, 64);
      pp += __shfl_xor(pp, 2, 64);
      if (cpart == 0) gstore(P.PART + bidb * 128 + jrow, pp);
    }
    __syncthreads();                         // drains vmcnt: h1 + PART acked
    if (tid == 0) ctradd(P.ep + EP_BCTR + (bidb & 15) * 16);
  }
}

__global__ __launch_bounds__(1024) void k_lstm(Params P){
  extern __shared__ __align__(16) uint32_t smem[];
  int bid = blockIdx.x;
  if (bid < NA) run_A(P, bid, smem);
  else run_B(P, bid - NA, smem);
}

// ---------------- pre-kernels ----------------
__global__ void k_init(const float* h0in, float* h0buf, float* h1buf, uint32_t* ep){
  int tid = threadIdx.x;
  for (int i = tid; i < HD; i += 256){
    float a = h0in[i], b = h0in[HD + i];
    h0buf[i] = a; h0buf[HD + i] = a;
    h1buf[i] = b; h1buf[HD + i] = b;
  }
  for (int i = tid; i < EP_N; i += 256) ep[i] = 0u;
}

// PRE[t][r] = b_ih0[r]+b_hh0[r] + sum_{k<118} W_ih0[r][k]*x[t][k]
__global__ void k_pre(const float* x, const float* Wih0, const float* bih0, const float* bhh0, float* PRE){
  int tb = blockIdx.x >> 2;
  int rc = blockIdx.x & 3;
  int tid = threadIdx.x;
  __shared__ float xl[32 * XDIM];
  for (int i = tid; i < 32 * XDIM; i += 256){
    int tt = i / XDIM, k = i % XDIM;
    xl[i] = x[(size_t)(tb * 32 + tt) * XDIM + k];
  }
  __syncthreads();
  for (int rr = 0; rr < 6; ++rr){
    int r = rc * HD + rr * 256 + tid;
    float acc[32];
#pragma unroll
    for (int t = 0; t < 32; ++t) acc[t] = 0.f;
    const float* wrow = Wih0 + (size_t)r * (XDIM + EMBD);
    for (int k = 0; k < XDIM; ++k){
      float wv = wrow[k];
#pragma unroll
      for (int t = 0; t < 32; ++t) acc[t] += wv * xl[t * XDIM + k];
    }
    float bb = bih0[r] + bhh0[r];
    for (int t = 0; t < 32; ++t)
      PRE[(size_t)(tb * 32 + t) * 6144 + r] = acc[t] + bb;
  }
}

// Wc = W_out @ W_hl (128x1536, K=1024); bc = W_out @ b_hl + b_out
__global__ void k_wc(const float* Whl, const float* Wout, const float* bhl, const float* bout,
                     float* Wc, float* bc){
  if (blockIdx.x == 96){
    int j = threadIdx.x;
    if (j < 128){
      float a = 0.f;
      for (int m = 0; m < 1024; ++m) a += Wout[(size_t)j * 1024 + m] * bhl[m];
      bc[j] = a + bout[j];
    }
    return;
  }
  int kt = blockIdx.x % 6, jt = blockIdx.x / 6;
  __shared__ float wo[8 * 1024];
  int tid = threadIdx.x;
  for (int i = tid; i < 8 * 1024; i += 256) wo[i] = Wout[(size_t)(jt * 8) * 1024 + i];
  __syncthreads();
  int k = kt * 256 + tid;
  float acc[8];
#pragma unroll
  for (int jj = 0; jj < 8; ++jj) acc[jj] = 0.f;
  for (int m = 0; m < 1024; ++m){
    float wl = Whl[(size_t)m * HD + k];
#pragma unroll
    for (int jj = 0; jj < 8; ++jj) acc[jj] += wo[jj * 1024 + m] * wl;
  }
#pragma unroll
  for (int jj = 0; jj < 8; ++jj) Wc[(size_t)(jt * 8 + jj) * HD + k] = acc[jj];
}

__global__ void k_sentinel(float* out){ out[0] = 1.0e6f; }

extern "C" void kernel_launch(void* const* d_in, const int* in_sizes, int n_in,
                              void* d_out, int out_size, void* d_ws, size_t ws_size,
                              hipStream_t stream){
  (void)in_sizes; (void)n_in; (void)out_size;
  const float* x    = (const float*)d_in[0];
  const float* h0in = (const float*)d_in[1];
  const float* c0in = (const float*)d_in[2];
  const float* Wih0 = (const float*)d_in[3];
  const float* Whh0 = (const float*)d_in[4];
  const float* bih0 = (const float*)d_in[5];
  const float* bhh0 = (const float*)d_in[6];
  const float* Wih1 = (const float*)d_in[7];
  const float* Whh1 = (const float*)d_in[8];
  const float* bih1 = (const float*)d_in[9];
  const float* bhh1 = (const float*)d_in[10];
  const float* Whl  = (const float*)d_in[11];
  const float* bhl  = (const float*)d_in[12];
  const float* Wout = (const float*)d_in[13];
  const float* bout = (const float*)d_in[14];
  const float* Wmap = (const float*)d_in[15];
  const float* bmap = (const float*)d_in[16];
  float* out = (float*)d_out;
  float* ws = (float*)d_ws;

  size_t off = 0;
  float* PRE    = ws + off; off += (size_t)T_STEPS * 6144;
  float* Wc     = ws + off; off += 128 * HD;
  float* bc     = ws + off; off += 128;
  float* h0buf  = ws + off; off += 2 * HD;
  float* h1buf  = ws + off; off += 2 * HD;
  float* PART   = ws + off; off += 128 * 128;
  off = (off + 63) & ~(size_t)63;
  uint32_t* ep  = (uint32_t*)(ws + off); off += EP_N;

  if (ws_size < off * sizeof(float) + 1024){
    hipLaunchKernelGGL(k_sentinel, dim3(1), dim3(1), 0, stream, out);
    return;
  }

  (void)hipFuncSetAttribute(reinterpret_cast<const void*>(k_lstm),
                            hipFuncAttributeMaxDynamicSharedMemorySize, SMEM_BYTES);

  hipLaunchKernelGGL(k_init, dim3(1), dim3(256), 0, stream, h0in, h0buf, h1buf, ep);
  hipLaunchKernelGGL(k_pre, dim3(256), dim3(256), 0, stream, x, Wih0, bih0, bhh0, PRE);
  hipLaunchKernelGGL(k_wc, dim3(97), dim3(256), 0, stream, Whl, Wout, bhl, bout, Wc, bc);

  Params P;
  P.x = x; P.h0in = h0in; P.c0in = c0in;
  P.Wih0 = Wih0; P.Whh0 = Whh0; P.bih0 = bih0; P.bhh0 = bhh0;
  P.Wih1 = Wih1; P.Whh1 = Whh1; P.bih1 = bih1; P.bhh1 = bhh1;
  P.Whl = Whl; P.bhl = bhl; P.Wout = Wout; P.bout = bout; P.Wmap = Wmap; P.bmap = bmap;
  P.PRE = PRE; P.Wc = Wc; P.bc = bc;
  P.h0buf = h0buf; P.h1buf = h1buf; P.PART = PART;
  P.ep = ep; P.out = out;

  hipLaunchKernelGGL(k_lstm, dim3(NBLK), dim3(1024), SMEM_BYTES, stream, P);
}

// Round 6
// 51662.665 us; speedup vs baseline: 1.2480x; 1.2480x over previous
//
#include <hip/hip_runtime.h>
#include <math.h>
#include <stdint.h>

#define T_STEPS 2048
#define XDIM 118
#define EMBD 128
#define HD 1536
#define NA 96
#define NB 128
#define NBLK (NA + NB)

// counter words, one 64B line each: ACTR lines 0..7 (word l*16, 12 A-blocks/line),
// BCTR lines at word 128+l*16 (16 B-blocks/line). Poll = one 8-lane load.
#define EP_ACTR 0
#define EP_BCTR 128
#define EP_N    256

// dynamic LDS: B needs 3072(xv) + 36864(weights) + 72 = 40008 words = 160032 B
#define SMEM_BYTES 160032

struct Params {
  const float *x, *h0in, *c0in;
  const float *Wih0, *Whh0, *bih0, *bhh0;
  const float *Wih1, *Whh1, *bih1, *bhh1;
  const float *Whl, *bhl, *Wout, *bout, *Wmap, *bmap;
  float *PRE, *Wc, *bc, *h0buf, *h1buf, *logits;
  uint32_t *ep;
  float *out;
};

__device__ __forceinline__ float bf_lo(uint32_t u){ return __uint_as_float(u << 16); }
__device__ __forceinline__ float bf_hi(uint32_t u){ return __uint_as_float(u & 0xffff0000u); }
__device__ __forceinline__ uint32_t packbf(float a, float b){
  uint32_t ua = __float_as_uint(a), ub = __float_as_uint(b);
  ua = (ua + 0x7fffu + ((ua >> 16) & 1u)) >> 16;           // RNE bf16 (low half)
  ub = (ub + 0x7fffu + ((ub >> 16) & 1u)) & 0xffff0000u;   // RNE bf16 (high half)
  return (ua & 0xffffu) | ub;
}
// Cross-block data via agent-scope relaxed atomics (served at the device coherence
// point -> never stale). data->flag order: __syncthreads() drains vmcnt (stores &
// non-returning atomics acked) before the counter add. Round-5 lesson: keep
// coherence-point traffic tiny — broadcast payloads are 512B (logits) / 6KB (h).
__device__ __forceinline__ float gload(const float* p){
  return __hip_atomic_load(p, __ATOMIC_RELAXED, __HIP_MEMORY_SCOPE_AGENT);
}
__device__ __forceinline__ void gstore(float* p, float v){
  __hip_atomic_store(p, v, __ATOMIC_RELAXED, __HIP_MEMORY_SCOPE_AGENT);
}
__device__ __forceinline__ uint32_t gloadu(const uint32_t* p){
  return __hip_atomic_load(p, __ATOMIC_RELAXED, __HIP_MEMORY_SCOPE_AGENT);
}
__device__ __forceinline__ void ctradd(uint32_t* p){
  (void)__hip_atomic_fetch_add(p, 1u, __ATOMIC_RELAXED, __HIP_MEMORY_SCOPE_AGENT);
}
__device__ __forceinline__ void faddg(float* p, float v){
  (void)__hip_atomic_fetch_add(p, v, __ATOMIC_RELAXED, __HIP_MEMORY_SCOPE_AGENT);
}
__device__ __forceinline__ float sigm(float x){ return 1.f / (1.f + __expf(-x)); }

// ---------------- group A: layer 0 + head (96 blocks, 16 outputs) ----------------
// wave w owns 4 gates of output O=bid*16+w. K=1664 in 13 slots of 128 (k=128p+2l,+1).
// Regs p=0..5; LDS q=0..2 (p=6..11); wremb=p12 (emb). Head reads finished 512B
// logits (B atomically pre-reduced) -> softmax -> Wmap -> emb, all local.
__device__ __forceinline__ float asrc(const Params& P, int r, int k){
  if (k < HD) return P.Whh0[(size_t)r * HD + k];
  return P.Wih0[(size_t)r * (XDIM + EMBD) + XDIM + (k - HD)];
}
__device__ void run_A(const Params& P, int bid, uint32_t* smem){
  const int tid = threadIdx.x;
  const int w = tid >> 6, l = tid & 63;
  const int O = bid * 16 + w;
  float* xv = (float*)smem;                   // [0,1664): h0 ++ emb
  uint2* wl2 = (uint2*)(smem + 1664);         // 3q*4g*1024 uint2 -> [1664, 26240)
  uint32_t* wmT = smem + 26240;               // bf16-packed Wmap^T, 8192 -> [26240,34432)
  float* pr2 = (float*)(smem + 34432);        // 2048 scratch (emb partials)
  float* lg   = (float*)(smem + 36480);       // 128
  float* plds = (float*)(smem + 36608);       // 128
  float* bcs  = (float*)(smem + 36736);       // 128
  float* bmaps= (float*)(smem + 36864);       // 128
  float* red2 = (float*)(smem + 36992);       // 2
  uint32_t wr[4][6], wremb[4];
#pragma unroll
  for (int g = 0; g < 4; ++g){
    int r = g * HD + O;
#pragma unroll
    for (int p = 0; p < 6; ++p)
      wr[g][p] = packbf(asrc(P, r, 128 * p + 2 * l), asrc(P, r, 128 * p + 2 * l + 1));
#pragma unroll
    for (int q = 0; q < 3; ++q){
      uint2 u;
      u.x = packbf(asrc(P, r, 128 * (6 + 2 * q) + 2 * l), asrc(P, r, 128 * (6 + 2 * q) + 2 * l + 1));
      u.y = packbf(asrc(P, r, 128 * (7 + 2 * q) + 2 * l), asrc(P, r, 128 * (7 + 2 * q) + 2 * l + 1));
      wl2[(q * 4 + g) * 1024 + tid] = u;
    }
    wremb[g] = packbf(asrc(P, r, 1536 + 2 * l), asrc(P, r, 1537 + 2 * l));
  }
  for (int idx = tid; idx < 8192; idx += 1024){   // wmT[k*64+e2] = pack(Wmap[2e2][k], Wmap[2e2+1][k])
    int e2 = idx & 63, k = idx >> 6;
    wmT[idx] = packbf(P.Wmap[(size_t)(2 * e2) * 128 + k], P.Wmap[(size_t)(2 * e2 + 1) * 128 + k]);
  }
  if (tid < 128){ bcs[tid] = P.bc[tid]; bmaps[tid] = P.bmap[tid]; }
  float cst = P.c0in[O];
  int alive = 1;                                   // wave-0 lanes only
  __syncthreads();
  for (int t = 0; t < T_STEPS; ++t){
    const float* pre = P.PRE + (size_t)t * 6144;   // prefetch early
    float q0 = pre[O], q1 = pre[HD + O], q2 = pre[2 * HD + O], q3 = pre[3 * HD + O];
    if (w == 0 && alive){                          // pre-wait: all-A(t-1) -> ACTR line >= 12t
      uint32_t tgt = 12u * (uint32_t)t, n = 0;
      while (1){
        uint32_t v = (l < 8) ? gloadu(P.ep + EP_ACTR + l * 16) : tgt;
        if (__all(v >= tgt)) break;
        if (++n > 5000000u){ alive = 0; break; }
      }
    }
    __syncthreads();
    // A0: zero logits[t&1] for B(t)'s atomic adds. Safe: pre-wait proves all
    // A(t-1) heads consumed it; B(t) is gated on all-A(t) (incl. this + drain).
    if (bid == 0 && tid < 128) gstore(P.logits + (t & 1) * 128 + tid, 0.f);
    const float* hp = P.h0buf + (((t & 1) ^ 1) * HD);
    xv[tid] = gload(hp + tid);
    if (tid < 512) xv[1024 + tid] = gload(hp + 1024 + tid);
    __syncthreads();
    float a0 = 0.f, a1 = 0.f, a2 = 0.f, a3 = 0.f;
#pragma unroll
    for (int p = 0; p < 6; ++p){
      float2 x2 = *(const float2*)&xv[128 * p + 2 * l];
      uint32_t u0 = wr[0][p], u1 = wr[1][p], u2 = wr[2][p], u3 = wr[3][p];
      a0 += bf_lo(u0) * x2.x + bf_hi(u0) * x2.y;
      a1 += bf_lo(u1) * x2.x + bf_hi(u1) * x2.y;
      a2 += bf_lo(u2) * x2.x + bf_hi(u2) * x2.y;
      a3 += bf_lo(u3) * x2.x + bf_hi(u3) * x2.y;
    }
#pragma unroll
    for (int q = 0; q < 3; ++q){
      float2 xa = *(const float2*)&xv[128 * (6 + 2 * q) + 2 * l];
      float2 xb = *(const float2*)&xv[128 * (7 + 2 * q) + 2 * l];
      uint2 u0 = wl2[(q * 4 + 0) * 1024 + tid];
      uint2 u1 = wl2[(q * 4 + 1) * 1024 + tid];
      uint2 u2 = wl2[(q * 4 + 2) * 1024 + tid];
      uint2 u3 = wl2[(q * 4 + 3) * 1024 + tid];
      a0 += bf_lo(u0.x) * xa.x + bf_hi(u0.x) * xa.y + bf_lo(u0.y) * xb.x + bf_hi(u0.y) * xb.y;
      a1 += bf_lo(u1.x) * xa.x + bf_hi(u1.x) * xa.y + bf_lo(u1.y) * xb.x + bf_hi(u1.y) * xb.y;
      a2 += bf_lo(u2.x) * xa.x + bf_hi(u2.x) * xa.y + bf_lo(u2.y) * xb.x + bf_hi(u2.y) * xb.y;
      a3 += bf_lo(u3.x) * xa.x + bf_hi(u3.x) * xa.y + bf_lo(u3.y) * xb.x + bf_hi(u3.y) * xb.y;
    }
    if (w == 0 && alive){                          // main wait: all-B(t-1) -> BCTR line >= 16t
      uint32_t tgt = 16u * (uint32_t)t, n = 0;
      while (1){
        uint32_t v = (l < 8) ? gloadu(P.ep + EP_BCTR + l * 16) : tgt;
        if (__all(v >= tgt)) break;
        if (++n > 5000000u){ alive = 0; break; }
      }
    }
    __syncthreads();
    if (t > 0){
      // ---- head: logits(t-1) [512B, pre-reduced] -> softmax -> out(A0) -> emb ----
      if (tid < 128) lg[tid] = gload(P.logits + ((t & 1) ^ 1) * 128 + tid) + bcs[tid];
      __syncthreads();
      if (tid < 64){
        float m = fmaxf(lg[tid], lg[tid + 64]);
#pragma unroll
        for (int k = 1; k < 64; k <<= 1) m = fmaxf(m, __shfl_xor(m, k, 64));
        float sd = __expf(lg[tid] - m) + __expf(lg[tid + 64] - m);
#pragma unroll
        for (int k = 1; k < 64; k <<= 1) sd += __shfl_xor(sd, k, 64);
        if (tid == 0){ red2[0] = m; red2[1] = 1.f / sd; }
      }
      __syncthreads();
      if (tid < 128){
        float pv = __expf(lg[tid] - red2[0]) * red2[1];
        plds[tid] = pv;
        if (bid == 0) P.out[(size_t)(t - 1) * 128 + tid] = pv;
      }
      __syncthreads();
      {   // emb[e] = bmap[e] + sum_i Wmap[e][i]*p[i]; thread (m=tid>>6, e2=tid&63)
        int e2 = tid & 63, m = tid >> 6;
        float s0 = 0.f, s1 = 0.f;
#pragma unroll
        for (int i = 0; i < 8; ++i){
          uint32_t u = wmT[(m * 8 + i) * 64 + e2];
          float p = plds[m * 8 + i];
          s0 += bf_lo(u) * p;
          s1 += bf_hi(u) * p;
        }
        *(float2*)&pr2[m * 128 + 2 * e2] = make_float2(s0, s1);
      }
      __syncthreads();
      if (tid < 128){
        float v = bmaps[tid];
#pragma unroll
        for (int m = 0; m < 16; ++m) v += pr2[m * 128 + tid];
        xv[1536 + tid] = v;
      }
    } else {
      if (tid < 128) xv[1536 + tid] = 0.f;         // emb(-1) = 0
    }
    __syncthreads();
    {   // p=12: emb slot
      float2 x2 = *(const float2*)&xv[1536 + 2 * l];
      a0 += bf_lo(wremb[0]) * x2.x + bf_hi(wremb[0]) * x2.y;
      a1 += bf_lo(wremb[1]) * x2.x + bf_hi(wremb[1]) * x2.y;
      a2 += bf_lo(wremb[2]) * x2.x + bf_hi(wremb[2]) * x2.y;
      a3 += bf_lo(wremb[3]) * x2.x + bf_hi(wremb[3]) * x2.y;
    }
#pragma unroll
    for (int m = 1; m < 64; m <<= 1){
      a0 += __shfl_xor(a0, m, 64);
      a1 += __shfl_xor(a1, m, 64);
      a2 += __shfl_xor(a2, m, 64);
      a3 += __shfl_xor(a3, m, 64);
    }
    float gi = sigm(a0 + q0);
    float gf = sigm(a1 + q1);
    float gg = tanhf(a2 + q2);
    float go = sigm(a3 + q3);
    cst = gf * cst + gi * gg;
    float hn = go * tanhf(cst);
    if (l == 0) gstore(P.h0buf + (t & 1) * HD + O, hn);
    __syncthreads();                               // drains vmcnt: h0 + zeroing acked
    if (tid == 0) ctradd(P.ep + EP_ACTR + (bid & 7) * 16);
  }
  if (bid == 0){                                   // epilogue: out[2047] from logits(2047)
    if (w == 0 && alive){
      uint32_t tgt = 16u * (uint32_t)T_STEPS, n = 0;
      while (1){
        uint32_t v = (l < 8) ? gloadu(P.ep + EP_BCTR + l * 16) : tgt;
        if (__all(v >= tgt)) break;
        if (++n > 5000000u){ alive = 0; break; }
      }
    }
    __syncthreads();
    if (tid < 128) lg[tid] = gload(P.logits + ((T_STEPS - 1) & 1) * 128 + tid) + bcs[tid];
    __syncthreads();
    if (tid < 64){
      float m = fmaxf(lg[tid], lg[tid + 64]);
#pragma unroll
      for (int k = 1; k < 64; k <<= 1) m = fmaxf(m, __shfl_xor(m, k, 64));
      float sd = __expf(lg[tid] - m) + __expf(lg[tid + 64] - m);
#pragma unroll
      for (int k = 1; k < 64; k <<= 1) sd += __shfl_xor(sd, k, 64);
      if (tid == 0){ red2[0] = m; red2[1] = 1.f / sd; }
    }
    __syncthreads();
    if (tid < 128) P.out[(size_t)(T_STEPS - 1) * 128 + tid] = __expf(lg[tid] - red2[0]) * red2[1];
  }
}

// ---------------- group B: LSTM layer 1 (128 blocks, 12 outputs each) ----------------
// waits: phase-1 <- BCTR>=16t (all-B(t-1)); phase-2 <- ACTR>=12(t+1) (all-A(t):
// h0(t) ready, logits[t&1] zeroed, logits(t-1) consumed). Wc-partials now go
// straight into logits[t&1] via fp32 atomic add (memory-side, fire-and-forget).
__device__ __forceinline__ float bsrc(const Params& P, int r, int k){
  if (k < HD) return P.Wih1[(size_t)r * HD + k];
  return P.Whh1[(size_t)r * HD + (k - HD)];
}
__device__ void run_B(const Params& P, int bidb, uint32_t* smem){
  const int tid = threadIdx.x;
  const int w = tid >> 6, l = tid & 63;
  const int base = bidb * 12;
  float* xv = (float*)smem;                  // 3072
  uint2* wl2 = (uint2*)(smem + 3072);        // 6q*3rows*1024 uint2 -> [3072, 39936)
  float* g1lds = (float*)(smem + 39936);     // 48
  float* c1lds = g1lds + 48;                 // 12
  float* h1lds = c1lds + 12;                 // 12
  uint32_t wr[3][12];
  float bias[3];
#pragma unroll
  for (int jj = 0; jj < 3; ++jj){
    int idx = 3 * w + jj;
    int g = idx / 12, o = idx % 12;
    int r = g * HD + base + o;
    bias[jj] = P.bih1[r] + P.bhh1[r];
#pragma unroll
    for (int p = 0; p < 12; ++p)
      wr[jj][p] = packbf(bsrc(P, r, 128 * p + 2 * l), bsrc(P, r, 128 * p + 2 * l + 1));
#pragma unroll
    for (int q = 0; q < 6; ++q){
      uint2 u;
      u.x = packbf(bsrc(P, r, 128 * (12 + 2 * q) + 2 * l), bsrc(P, r, 128 * (12 + 2 * q) + 2 * l + 1));
      u.y = packbf(bsrc(P, r, 128 * (13 + 2 * q) + 2 * l), bsrc(P, r, 128 * (13 + 2 * q) + 2 * l + 1));
      wl2[(q * 3 + jj) * 1024 + tid] = u;
    }
  }
  const int jrow = tid >> 2, cpart = tid & 3;
  float wc0 = 0.f, wc1 = 0.f, wc2 = 0.f;
  if (tid < 512){
    const float* wcp = P.Wc + (size_t)jrow * HD + base + cpart * 3;
    wc0 = wcp[0]; wc1 = wcp[1]; wc2 = wcp[2];
  }
  if (tid < 12) c1lds[tid] = P.c0in[HD + base + tid];
  int alive = 1;
  __syncthreads();
  for (int t = 0; t < T_STEPS; ++t){
    if (w == 0 && alive){                    // all-B(t-1): h1(t-1) complete, self-barrier
      uint32_t tgt = 16u * (uint32_t)t, n = 0;
      while (1){
        uint32_t v = (l < 8) ? gloadu(P.ep + EP_BCTR + l * 16) : tgt;
        if (__all(v >= tgt)) break;
        if (++n > 5000000u){ alive = 0; break; }
      }
    }
    __syncthreads();
    const float* h1p = P.h1buf + (((t & 1) ^ 1) * HD);
    xv[1536 + tid] = gload(h1p + tid);
    if (tid < 512) xv[2560 + tid] = gload(h1p + 1024 + tid);
    __syncthreads();
    float a0 = 0.f, a1 = 0.f, a2 = 0.f;
#pragma unroll
    for (int q = 0; q < 6; ++q){             // h1 side (LDS weights) — overlapped phase
      float2 xa = *(const float2*)&xv[128 * (12 + 2 * q) + 2 * l];
      float2 xb = *(const float2*)&xv[128 * (13 + 2 * q) + 2 * l];
      uint2 u0 = wl2[(q * 3 + 0) * 1024 + tid];
      uint2 u1 = wl2[(q * 3 + 1) * 1024 + tid];
      uint2 u2 = wl2[(q * 3 + 2) * 1024 + tid];
      a0 += bf_lo(u0.x) * xa.x + bf_hi(u0.x) * xa.y + bf_lo(u0.y) * xb.x + bf_hi(u0.y) * xb.y;
      a1 += bf_lo(u1.x) * xa.x + bf_hi(u1.x) * xa.y + bf_lo(u1.y) * xb.x + bf_hi(u1.y) * xb.y;
      a2 += bf_lo(u2.x) * xa.x + bf_hi(u2.x) * xa.y + bf_lo(u2.y) * xb.x + bf_hi(u2.y) * xb.y;
    }
    if (w == 0 && alive){                    // all-A(t): h0(t) ready, logits[t&1] zeroed
      uint32_t tgt = 12u * (uint32_t)(t + 1), n = 0;
      while (1){
        uint32_t v = (l < 8) ? gloadu(P.ep + EP_ACTR + l * 16) : tgt;
        if (__all(v >= tgt)) break;
        if (++n > 5000000u){ alive = 0; break; }
      }
    }
    __syncthreads();
    const float* h0p = P.h0buf + (t & 1) * HD;
    xv[tid] = gload(h0p + tid);
    if (tid < 512) xv[1024 + tid] = gload(h0p + 1024 + tid);
    __syncthreads();
#pragma unroll
    for (int p = 0; p < 12; ++p){            // h0 side (reg weights) — serial phase
      float2 x2 = *(const float2*)&xv[128 * p + 2 * l];
      uint32_t u0 = wr[0][p], u1 = wr[1][p], u2 = wr[2][p];
      a0 += bf_lo(u0) * x2.x + bf_hi(u0) * x2.y;
      a1 += bf_lo(u1) * x2.x + bf_hi(u1) * x2.y;
      a2 += bf_lo(u2) * x2.x + bf_hi(u2) * x2.y;
    }
#pragma unroll
    for (int m = 1; m < 64; m <<= 1){
      a0 += __shfl_xor(a0, m, 64);
      a1 += __shfl_xor(a1, m, 64);
      a2 += __shfl_xor(a2, m, 64);
    }
    if (l == 0){
      g1lds[3 * w + 0] = a0 + bias[0];
      g1lds[3 * w + 1] = a1 + bias[1];
      g1lds[3 * w + 2] = a2 + bias[2];
    }
    __syncthreads();
    if (tid < 12){
      int o = tid;
      float gi = sigm(g1lds[o]);
      float gf = sigm(g1lds[12 + o]);
      float gg = tanhf(g1lds[24 + o]);
      float go = sigm(g1lds[36 + o]);
      float c = gf * c1lds[o] + gi * gg;
      c1lds[o] = c;
      float hn = go * tanhf(c);
      h1lds[o] = hn;
      gstore(P.h1buf + (t & 1) * HD + base + o, hn);
    }
    __syncthreads();
    if (tid < 512){
      float pp = wc0 * h1lds[cpart * 3] + wc1 * h1lds[cpart * 3 + 1] + wc2 * h1lds[cpart * 3 + 2];
      pp += __shfl_xor(pp, 1, 64);
      pp += __shfl_xor(pp, 2, 64);
      if (cpart == 0) faddg(P.logits + (t & 1) * 128 + jrow, pp);   // pre-reduced logits
    }
    __syncthreads();                         // drains vmcnt: h1 stores + logit adds acked
    if (tid == 0) ctradd(P.ep + EP_BCTR + (bidb & 7) * 16);
  }
}

__global__ __launch_bounds__(1024) void k_lstm(Params P){
  extern __shared__ __align__(16) uint32_t smem[];
  int bid = blockIdx.x;
  if (bid < NA) run_A(P, bid, smem);
  else run_B(P, bid - NA, smem);
}

// ---------------- pre-kernels ----------------
__global__ void k_init(const float* h0in, float* h0buf, float* h1buf, float* logits,
                       uint32_t* ep){
  int tid = threadIdx.x;
  for (int i = tid; i < HD; i += 256){
    float a = h0in[i], b = h0in[HD + i];
    h0buf[i] = a; h0buf[HD + i] = a;
    h1buf[i] = b; h1buf[HD + i] = b;
  }
  if (tid < 256) logits[tid] = 0.f;
  for (int i = tid; i < EP_N; i += 256) ep[i] = 0u;
}

// PRE[t][r] = b_ih0[r]+b_hh0[r] + sum_{k<118} W_ih0[r][k]*x[t][k]
__global__ void k_pre(const float* x, const float* Wih0, const float* bih0, const float* bhh0, float* PRE){
  int tb = blockIdx.x >> 2;
  int rc = blockIdx.x & 3;
  int tid = threadIdx.x;
  __shared__ float xl[32 * XDIM];
  for (int i = tid; i < 32 * XDIM; i += 256){
    int tt = i / XDIM, k = i % XDIM;
    xl[i] = x[(size_t)(tb * 32 + tt) * XDIM + k];
  }
  __syncthreads();
  for (int rr = 0; rr < 6; ++rr){
    int r = rc * HD + rr * 256 + tid;
    float acc[32];
#pragma unroll
    for (int t = 0; t < 32; ++t) acc[t] = 0.f;
    const float* wrow = Wih0 + (size_t)r * (XDIM + EMBD);
    for (int k = 0; k < XDIM; ++k){
      float wv = wrow[k];
#pragma unroll
      for (int t = 0; t < 32; ++t) acc[t] += wv * xl[t * XDIM + k];
    }
    float bb = bih0[r] + bhh0[r];
    for (int t = 0; t < 32; ++t)
      PRE[(size_t)(tb * 32 + t) * 6144 + r] = acc[t] + bb;
  }
}

// Wc = W_out @ W_hl (128x1536, K=1024); bc = W_out @ b_hl + b_out
__global__ void k_wc(const float* Whl, const float* Wout, const float* bhl, const float* bout,
                     float* Wc, float* bc){
  if (blockIdx.x == 96){
    int j = threadIdx.x;
    if (j < 128){
      float a = 0.f;
      for (int m = 0; m < 1024; ++m) a += Wout[(size_t)j * 1024 + m] * bhl[m];
      bc[j] = a + bout[j];
    }
    return;
  }
  int kt = blockIdx.x % 6, jt = blockIdx.x / 6;
  __shared__ float wo[8 * 1024];
  int tid = threadIdx.x;
  for (int i = tid; i < 8 * 1024; i += 256) wo[i] = Wout[(size_t)(jt * 8) * 1024 + i];
  __syncthreads();
  int k = kt * 256 + tid;
  float acc[8];
#pragma unroll
  for (int jj = 0; jj < 8; ++jj) acc[jj] = 0.f;
  for (int m = 0; m < 1024; ++m){
    float wl = Whl[(size_t)m * HD + k];
#pragma unroll
    for (int jj = 0; jj < 8; ++jj) acc[jj] += wo[jj * 1024 + m] * wl;
  }
#pragma unroll
  for (int jj = 0; jj < 8; ++jj) Wc[(size_t)(jt * 8 + jj) * HD + k] = acc[jj];
}

__global__ void k_sentinel(float* out){ out[0] = 1.0e6f; }

extern "C" void kernel_launch(void* const* d_in, const int* in_sizes, int n_in,
                              void* d_out, int out_size, void* d_ws, size_t ws_size,
                              hipStream_t stream){
  (void)in_sizes; (void)n_in; (void)out_size;
  const float* x    = (const float*)d_in[0];
  const float* h0in = (const float*)d_in[1];
  const float* c0in = (const float*)d_in[2];
  const float* Wih0 = (const float*)d_in[3];
  const float* Whh0 = (const float*)d_in[4];
  const float* bih0 = (const float*)d_in[5];
  const float* bhh0 = (const float*)d_in[6];
  const float* Wih1 = (const float*)d_in[7];
  const float* Whh1 = (const float*)d_in[8];
  const float* bih1 = (const float*)d_in[9];
  const float* bhh1 = (const float*)d_in[10];
  const float* Whl  = (const float*)d_in[11];
  const float* bhl  = (const float*)d_in[12];
  const float* Wout = (const float*)d_in[13];
  const float* bout = (const float*)d_in[14];
  const float* Wmap = (const float*)d_in[15];
  const float* bmap = (const float*)d_in[16];
  float* out = (float*)d_out;
  float* ws = (float*)d_ws;

  size_t off = 0;
  float* PRE    = ws + off; off += (size_t)T_STEPS * 6144;
  float* Wc     = ws + off; off += 128 * HD;
  float* bc     = ws + off; off += 128;
  float* h0buf  = ws + off; off += 2 * HD;
  float* h1buf  = ws + off; off += 2 * HD;
  off = (off + 63) & ~(size_t)63;
  float* logits = ws + off; off += 256;
  off = (off + 63) & ~(size_t)63;
  uint32_t* ep  = (uint32_t*)(ws + off); off += EP_N;

  if (ws_size < off * sizeof(float) + 1024){
    hipLaunchKernelGGL(k_sentinel, dim3(1), dim3(1), 0, stream, out);
    return;
  }

  (void)hipFuncSetAttribute(reinterpret_cast<const void*>(k_lstm),
                            hipFuncAttributeMaxDynamicSharedMemorySize, SMEM_BYTES);

  hipLaunchKernelGGL(k_init, dim3(1), dim3(256), 0, stream, h0in, h0buf, h1buf, logits, ep);
  hipLaunchKernelGGL(k_pre, dim3(256), dim3(256), 0, stream, x, Wih0, bih0, bhh0, PRE);
  hipLaunchKernelGGL(k_wc, dim3(97), dim3(256), 0, stream, Whl, Wout, bhl, bout, Wc, bc);

  Params P;
  P.x = x; P.h0in = h0in; P.c0in = c0in;
  P.Wih0 = Wih0; P.Whh0 = Whh0; P.bih0 = bih0; P.bhh0 = bhh0;
  P.Wih1 = Wih1; P.Whh1 = Whh1; P.bih1 = bih1; P.bhh1 = bhh1;
  P.Whl = Whl; P.bhl = bhl; P.Wout = Wout; P.bout = bout; P.Wmap = Wmap; P.bmap = bmap;
  P.PRE = PRE; P.Wc = Wc; P.bc = bc;
  P.h0buf = h0buf; P.h1buf = h1buf; P.logits = logits;
  P.ep = ep; P.out = out;

  hipLaunchKernelGGL(k_lstm, dim3(NBLK), dim3(1024), SMEM_BYTES, stream, P);
}